// Round 14
// baseline (322.977 us; speedup 1.0000x reference)
//
#include <hip/hip_runtime.h>

#define VOCAB 65536
#define NELEM 4194304      // 256*16*32*32
#define BHW   262144       // 256*1024

__device__ __forceinline__ double cubic_d(double t) {
  const double a = -0.75;
  t = fabs(t);
  if (t <= 1.0) return ((a + 2.0) * t - (a + 3.0)) * t * t + 1.0;
  if (t < 2.0)  return a * (((t - 5.0) * t + 8.0) * t - 4.0);
  return 0.0;
}

// PN=32 idx slot: XOR swizzle, bijective, conflict-free both directions.
__device__ __forceinline__ int idx32_slot(int x, int y) { return (x << 5) | ((y ^ x) & 31); }

// 512 threads: x0=(t&3)*8, y=(t>>2)&31, g=t>>7 (wave-uniform, SGPR) owns ch 4g..4g+3.
// Entire h chain is f64 (bit-identical to the passing r11 kernel).
template<int PN>
__device__ __forceinline__ void process_scale(
    int si, int phi_idx,
    const float* __restrict__ phi_w, const float* __restrict__ phi_b,
    float* __restrict__ hist, double* __restrict__ acc,
    const float (&fown)[4][8], double (&fhat)[4][8],
    double* __restrict__ hupd, unsigned* __restrict__ idxL,
    float* __restrict__ wMT, double* __restrict__ red,
    int t, int y, int g, int x0)
{
  constexpr int CELLS = PN * PN;
  constexpr int S = 32 / PN;
  const int w = t >> 6;   // 8 waves

  // ---------- P0: zero idx, wM; stage resid + entropy/psum + PREV mse ----------
  idxL[t] = 0u; idxL[t + 512] = 0u;
  if constexpr (PN != 32) {
    if (t < 32) {
      #pragma unroll
      for (int q = 0; q < PN; ++q) wMT[q * 32 + t] = 0.0f;
      double xp = ((double)t + 0.5) * (double)PN / 32.0 - 0.5;
      int q0i = (int)floor(xp);
      for (int k = 0; k < 4; ++k) {
        int j = q0i + k - 1;
        int jc = j < 0 ? 0 : (j > PN - 1 ? PN - 1 : j);
        wMT[jc * 32 + t] += (float)cubic_d(xp - (double)j);   // f32 accumulate == np M build
      }
    }
    double mseP = 0.0;
    float entf = 0.0f, ps0 = 0, ps1 = 0, ps2 = 0, ps3 = 0;
    #pragma unroll
    for (int cc = 0; cc < 4; ++cc) {
      double* hp = hupd + (4 * g + cc) * 1056 + y * 33 + x0;
      float psl = 0.0f;
      #pragma unroll
      for (int k = 0; k < 8; ++k) {
        double xr = (double)fown[cc][k] - fhat[cc][k];
        hp[k] = xr;
        mseP += xr * xr;                                  // prev scale's mse term
        float pr = 1.0f / (1.0f + __expf(400.0f * (float)xr));   // sigmoid(-400 x)
        entf -= pr * __logf(pr + 1e-5f) + (1.0f - pr) * __logf(1.0f - pr + 1e-5f);
        psl += pr;
      }
      if (cc == 0) ps0 = psl; else if (cc == 1) ps1 = psl; else if (cc == 2) ps2 = psl; else ps3 = psl;
    }
    double ent_d = (double)entf;
    #pragma unroll
    for (int off = 32; off > 0; off >>= 1) {
      mseP  += __shfl_down(mseP, off);
      ent_d += __shfl_down(ent_d, off);
      ps0 += __shfl_down(ps0, off); ps1 += __shfl_down(ps1, off);
      ps2 += __shfl_down(ps2, off); ps3 += __shfl_down(ps3, off);
    }
    if ((t & 63) == 0) {
      red[w * 8 + 0] = mseP; red[w * 8 + 1] = ent_d;
      red[w * 8 + 2] = (double)ps0; red[w * 8 + 3] = (double)ps1;
      red[w * 8 + 4] = (double)ps2; red[w * 8 + 5] = (double)ps3;
    }
  }
  __syncthreads();

  if constexpr (PN != 32) {   // flush block reductions
    if (t == 0) {
      double m = 0.0, e = 0.0;
      #pragma unroll
      for (int ww = 0; ww < 8; ++ww) { m += red[ww * 8]; e += red[ww * 8 + 1]; }
      if (si > 0) atomicAdd(&acc[(si - 1) * 18 + 0], m);
      atomicAdd(&acc[si * 18 + 1], e);
    }
    if (t < 16) {
      int gg = t >> 2, cc = t & 3;
      atomicAdd(&acc[si * 18 + 2 + t], red[(2 * gg) * 8 + 2 + cc] + red[(2 * gg + 1) * 8 + 2 + cc]);
    }
  }

  // ---------- P2: quantize (sign of f64 cell sums) ----------
  if constexpr (PN == 32) {
    double mseP = 0.0;
    float entf = 0.0f, ps0 = 0, ps1 = 0, ps2 = 0, ps3 = 0;
    unsigned bb[8] = {0, 0, 0, 0, 0, 0, 0, 0};
    #pragma unroll
    for (int cc = 0; cc < 4; ++cc) {
      float psl = 0.0f;
      #pragma unroll
      for (int k = 0; k < 8; ++k) {
        double xr = (double)fown[cc][k] - fhat[cc][k];
        if (xr > 0.0) bb[k] |= (1u << cc);
        mseP += xr * xr;
        float pr = 1.0f / (1.0f + __expf(400.0f * (float)xr));
        entf -= pr * __logf(pr + 1e-5f) + (1.0f - pr) * __logf(1.0f - pr + 1e-5f);
        psl += pr;
      }
      if (cc == 0) ps0 = psl; else if (cc == 1) ps1 = psl; else if (cc == 2) ps2 = psl; else ps3 = psl;
    }
    #pragma unroll
    for (int k = 0; k < 8; ++k)
      if (bb[k]) atomicOr(&idxL[idx32_slot(x0 + k, y)], bb[k] << (4 * g));
    double ent_d = (double)entf;
    #pragma unroll
    for (int off = 32; off > 0; off >>= 1) {
      mseP  += __shfl_down(mseP, off);
      ent_d += __shfl_down(ent_d, off);
      ps0 += __shfl_down(ps0, off); ps1 += __shfl_down(ps1, off);
      ps2 += __shfl_down(ps2, off); ps3 += __shfl_down(ps3, off);
    }
    if ((t & 63) == 0) {
      red[w * 8 + 0] = mseP; red[w * 8 + 1] = ent_d;
      red[w * 8 + 2] = (double)ps0; red[w * 8 + 3] = (double)ps1;
      red[w * 8 + 4] = (double)ps2; red[w * 8 + 5] = (double)ps3;
    }
  } else if constexpr (PN == 16) {
    int cell = t & 255;
    int i0 = (cell >> 4) * 2, j0 = (cell & 15) * 2;
    unsigned bits = 0;
    #pragma unroll
    for (int k = 0; k < 8; ++k) {
      int c = (t >> 8) + 2 * k;
      const double* hp = hupd + c * 1056 + i0 * 33 + j0;
      double s = hp[0] + hp[1] + hp[33] + hp[34];
      if (s > 0.0) bits |= (1u << c);
    }
    atomicOr(&idxL[cell], bits);
  } else if constexpr (PN == 8) {
    #pragma unroll
    for (int k = 0; k < 2; ++k) {
      int task = t + 512 * k;
      int c = task >> 6, cell = task & 63;
      const double* hp = hupd + c * 1056 + ((cell >> 3) * 4) * 33 + (cell & 7) * 4;
      double s = 0.0;
      #pragma unroll
      for (int dy = 0; dy < 4; ++dy)
        #pragma unroll
        for (int dx = 0; dx < 4; ++dx) s += hp[dy * 33 + dx];
      if (s > 0.0) atomicOr(&idxL[cell], 1u << c);
    }
  } else {   // PN 1,2,4
    constexpr int TASKS = 16 * CELLS;     // 16, 64, 256
    constexpr int G = 512 / TASKS;        // 32, 8, 2
    int p = t / G, sub = t % G;
    int c = p / CELLS, cell = p % CELLS;
    const double* hp = hupd + c * 1056 + ((cell / PN) * S) * 33 + (cell % PN) * S;
    double s = 0.0;
    for (int e = sub; e < S * S; e += G) s += hp[(e / S) * 33 + (e % S)];
    #pragma unroll
    for (int off = G / 2; off > 0; off >>= 1) s += __shfl_down(s, off, G);
    if (sub == 0 && s > 0.0) atomicOr(&idxL[cell], 1u << c);
  }
  __syncthreads();

  if constexpr (PN == 32) {   // flush scale-4 mse + scale-5 ent/ps
    if (t == 0) {
      double m = 0.0, e = 0.0;
      #pragma unroll
      for (int ww = 0; ww < 8; ++ww) { m += red[ww * 8]; e += red[ww * 8 + 1]; }
      atomicAdd(&acc[4 * 18 + 0], m);
      atomicAdd(&acc[5 * 18 + 1], e);
    }
    if (t < 16) {
      int gg = t >> 2, cc = t & 3;
      atomicAdd(&acc[5 * 18 + 2 + t], red[(2 * gg) * 8 + 2 + cc] + red[(2 * gg + 1) * 8 + 2 + cc]);
    }
  }

  // ---------- P3: hist + upsample codes -> hupd ----------
  if constexpr (PN == 32) {
    atomicAdd(&hist[5 * VOCAB + idxL[t]], 1.0f);         // swizzle bijective
    atomicAdd(&hist[5 * VOCAB + idxL[t + 512]], 1.0f);
  } else {
    if (t < CELLS) atomicAdd(&hist[(size_t)si * VOCAB + idxL[t]], 1.0f);
  }
  {
    int c2 = t >> 5, y2 = t & 31;
    double* hrow = hupd + c2 * 1056 + y2 * 33;
    if constexpr (PN == 32) {
      #pragma unroll
      for (int x = 0; x < 32; ++x)
        hrow[x] = ((idxL[idx32_slot(x, y2)] >> c2) & 1) ? 1.0 : -1.0;
    } else {
      constexpr int QC = (PN < 4) ? PN : 4;
      #pragma unroll
      for (int q0 = 0; q0 < PN; q0 += QC) {
        double tmp[QC];
        #pragma unroll
        for (int qq = 0; qq < QC; ++qq) tmp[qq] = 0.0;
        #pragma unroll
        for (int r = 0; r < PN; ++r) {
          double ww = (double)wMT[r * 32 + y2];
          #pragma unroll
          for (int qq = 0; qq < QC; ++qq) {
            double sg = ((idxL[r * PN + q0 + qq] >> c2) & 1) ? 1.0 : -1.0;
            tmp[qq] = fma(ww, sg, tmp[qq]);
          }
        }
        #pragma unroll
        for (int x = 0; x < 32; ++x) {
          double s2 = (q0 == 0) ? 0.0 : hrow[x];
          #pragma unroll
          for (int qq = 0; qq < QC; ++qq)
            s2 = fma((double)wMT[(q0 + qq) * 32 + x], tmp[qq], s2);
          hrow[x] = s2;
        }
      }
    }
  }
  __syncthreads();

  // ---------- P4: seed fhat, conv3x3 into fhat (0.5-scaled weights from SGPR) ----------
  const float* wgbase = phi_w + phi_idx * 2304;   // wave-uniform -> scalar loads
  #pragma unroll
  for (int cc = 0; cc < 4; ++cc) {
    double bh = 0.5 * (double)phi_b[phi_idx * 16 + 4 * g + cc];
    const double* hu = hupd + (4 * g + cc) * 1056 + y * 33 + x0;
    #pragma unroll
    for (int k = 0; k < 8; ++k)
      fhat[cc][k] = fhat[cc][k] + 0.5 * hu[k] + bh;
  }
  for (int ci = 0; ci < 16; ++ci) {
    const double* hbase = hupd + ci * 1056;
    #pragma unroll
    for (int dy = 0; dy < 3; ++dy) {
      int ry = y + dy - 1;
      if (ry < 0 || ry > 31) continue;
      double prow[10];
      const double* hr = hbase + ry * 33;
      // interior taps are statically in-range; only the two halo taps need selects
      prow[0] = (x0 == 0)  ? 0.0 : hr[x0 - 1];
      #pragma unroll
      for (int jj = 1; jj < 9; ++jj) prow[jj] = hr[x0 - 1 + jj];
      prow[9] = (x0 == 24) ? 0.0 : hr[x0 + 8];
      #pragma unroll
      for (int cc = 0; cc < 4; ++cc) {
        const float* wp = wgbase + ((4 * g + cc) * 16 + ci) * 9 + dy * 3;  // SGPR addr
        double w0 = 0.5 * (double)wp[0], w1 = 0.5 * (double)wp[1], w2 = 0.5 * (double)wp[2];
        #pragma unroll
        for (int k = 0; k < 8; ++k)
          fhat[cc][k] = fma(w0, prow[k], fma(w1, prow[k + 1], fma(w2, prow[k + 2], fhat[cc][k])));
      }
    }
  }
  __syncthreads();
}

__global__ __launch_bounds__(512) void lfq_all(
    const float* __restrict__ f, const float* __restrict__ phi_w,
    const float* __restrict__ phi_b, float* __restrict__ fhi,
    float* __restrict__ hist, double* __restrict__ acc,
    unsigned* __restrict__ cnt, float* __restrict__ total)
{
  __shared__ double   hupd[16 * 1056];   // 135168 B
  __shared__ unsigned idxL[1024];
  __shared__ float    wMT[512];          // bicubic M transposed [PN][32]
  __shared__ double   red[64];           // 8 waves x 8 slots
  __shared__ unsigned lastflag;

  const int t = threadIdx.x;
  const int y = (t >> 2) & 31;
  const int x0 = (t & 3) * 8;
  const int g = __builtin_amdgcn_readfirstlane(t >> 7);   // wave-uniform -> SGPR
  const size_t ibase = (size_t)blockIdx.x * 16384;
  const int w = t >> 6;

  float fown[4][8];
  double fhat[4][8];
  #pragma unroll
  for (int cc = 0; cc < 4; ++cc) {
    const float* fp = f + ibase + (size_t)(4 * g + cc) * 1024 + y * 32 + x0;
    float4 fa = *(const float4*)fp;
    float4 fb = *(const float4*)(fp + 4);
    fown[cc][0] = fa.x; fown[cc][1] = fa.y; fown[cc][2] = fa.z; fown[cc][3] = fa.w;
    fown[cc][4] = fb.x; fown[cc][5] = fb.y; fown[cc][6] = fb.z; fown[cc][7] = fb.w;
    #pragma unroll
    for (int k = 0; k < 8; ++k) fhat[cc][k] = 0.0;
  }

  // PHI_IDX = [0,0,1,2,3,3]
  process_scale<1 >(0, 0, phi_w, phi_b, hist, acc, fown, fhat, hupd, idxL, wMT, red, t, y, g, x0);
  process_scale<2 >(1, 0, phi_w, phi_b, hist, acc, fown, fhat, hupd, idxL, wMT, red, t, y, g, x0);
  process_scale<4 >(2, 1, phi_w, phi_b, hist, acc, fown, fhat, hupd, idxL, wMT, red, t, y, g, x0);
  process_scale<8 >(3, 2, phi_w, phi_b, hist, acc, fown, fhat, hupd, idxL, wMT, red, t, y, g, x0);
  process_scale<16>(4, 3, phi_w, phi_b, hist, acc, fown, fhat, hupd, idxL, wMT, red, t, y, g, x0);
  process_scale<32>(5, 3, phi_w, phi_b, hist, acc, fown, fhat, hupd, idxL, wMT, red, t, y, g, x0);

  // final (scale 6) mse
  double mse = 0.0;
  #pragma unroll
  for (int cc = 0; cc < 4; ++cc)
    #pragma unroll
    for (int k = 0; k < 8; ++k) {
      double d = fhat[cc][k] - (double)fown[cc][k];
      mse += d * d;
    }
  #pragma unroll
  for (int off = 32; off > 0; off >>= 1) mse += __shfl_down(mse, off);
  if ((t & 63) == 0) red[w * 8] = mse;
  __syncthreads();
  if (t == 0) {
    double m = 0.0;
    #pragma unroll
    for (int ww = 0; ww < 8; ++ww) m += red[ww * 8];
    atomicAdd(&acc[5 * 18 + 0], m);
  }

  // output
  #pragma unroll
  for (int cc = 0; cc < 4; ++cc) {
    float* op = fhi + ibase + (size_t)(4 * g + cc) * 1024 + y * 32 + x0;
    *(float4*)op = make_float4((float)fhat[cc][0], (float)fhat[cc][1],
                               (float)fhat[cc][2], (float)fhat[cc][3]);
    *(float4*)(op + 4) = make_float4((float)fhat[cc][4], (float)fhat[cc][5],
                                     (float)fhat[cc][6], (float)fhat[cc][7]);
  }

  // ---------- last-block finalize (replaces the separate finalize kernel) ----------
  __threadfence();
  if (t == 0) {
    unsigned old = atomicAdd(cnt, 1u);
    lastflag = (old == 255u) ? 1u : 0u;
  }
  __syncthreads();
  if (lastflag) {
    __threadfence();
    // lanes 0..95: one (si,cc) codebook-entropy term each (96 logs across 2 waves)
    double q = 0.0;
    if (t < 96) {
      int si = t >> 4, cc = t & 15;
      double ap0 = acc[si * 18 + 2 + cc] / (double)BHW;
      double ap1 = 1.0 - ap0;
      q = ap0 * log(ap0 + 1e-5) + ap1 * log(ap1 + 1e-5);
    }
    #pragma unroll
    for (int off = 32; off > 0; off >>= 1) q += __shfl_down(q, off);
    if (t < 512 && (t & 63) == 0) red[t >> 6] = q;
    __syncthreads();
    if (t == 0) {
      double qsum = red[0] + red[1];           // sum of all -codebook-entropy terms (signed)
      double vq = 0.0, pse = 0.0;
      for (int si = 0; si < 6; ++si) {
        vq  += acc[si * 18 + 0];
        pse += acc[si * 18 + 1] / (double)BHW;
      }
      double ent = pse + qsum;                 // ent = sum(pse) - sum(ce), ce = -sum(q)
      *total = (float)(1.25 * vq / ((double)NELEM * 6.0) + (0.1 / 6.0) * ent);
    }
  }
}

extern "C" void kernel_launch(void* const* d_in, const int* in_sizes, int n_in,
                              void* d_out, int out_size, void* d_ws, size_t ws_size,
                              hipStream_t stream)
{
  const float* f     = (const float*)d_in[0];
  const float* phi_w = (const float*)d_in[1];
  const float* phi_b = (const float*)d_in[2];
  float* out   = (float*)d_out;
  float* fhi   = out;                 // fully overwritten
  float* total = out + NELEM;
  float* hist  = out + NELEM + 1;     // 6*65536
  double* acc  = (double*)d_ws;       // 108 doubles
  unsigned* cnt = (unsigned*)((char*)d_ws + 960);   // block counter (within the zeroed 1 KB)

  hipMemsetAsync((void*)(out + NELEM), 0, (size_t)(1 + 6 * VOCAB) * sizeof(float), stream);
  hipMemsetAsync(d_ws, 0, 1024, stream);

  lfq_all<<<256, 512, 0, stream>>>(f, phi_w, phi_b, fhi, hist, acc, cnt, total);
}

// Round 15
// 297.284 us; speedup vs baseline: 1.0864x; 1.0864x over previous
//
#include <hip/hip_runtime.h>

#define VOCAB 65536
#define NELEM 4194304      // 256*16*32*32
#define BHW   262144       // 256*1024

__device__ __forceinline__ double cubic_d(double t) {
  const double a = -0.75;
  t = fabs(t);
  if (t <= 1.0) return ((a + 2.0) * t - (a + 3.0)) * t * t + 1.0;
  if (t < 2.0)  return a * (((t - 5.0) * t + 8.0) * t - 4.0);
  return 0.0;
}

// PN=32 idx slot: XOR swizzle, bijective, conflict-free both directions.
__device__ __forceinline__ int idx32_slot(int x, int y) { return (x << 5) | ((y ^ x) & 31); }

// 512 threads: x0=(t&3)*8, y=(t>>2)&31, g=t>>7 (wave-uniform, SGPR) owns ch 4g..4g+3.
// Entire h chain is f64 (bit-identical to the passing r9/r11 kernels).
template<int PN>
__device__ __forceinline__ void process_scale(
    int si, int phi_idx,
    const float* __restrict__ phi_w, const float* __restrict__ phi_b,
    float* __restrict__ hist, double* __restrict__ acc,
    const float (&fown)[4][8], double (&fhat)[4][8],
    double* __restrict__ hupd, unsigned* __restrict__ idxL,
    float* __restrict__ wMT, double* __restrict__ red,
    int t, int y, int g, int x0)
{
  constexpr int CELLS = PN * PN;
  constexpr int S = 32 / PN;
  const int w = t >> 6;   // 8 waves

  // ---------- P0: zero idx, wM; stage resid + entropy/psum + PREV mse ----------
  idxL[t] = 0u; idxL[t + 512] = 0u;
  if constexpr (PN != 32) {
    if (t < 32) {
      #pragma unroll
      for (int q = 0; q < PN; ++q) wMT[q * 32 + t] = 0.0f;
      double xp = ((double)t + 0.5) * (double)PN / 32.0 - 0.5;
      int q0i = (int)floor(xp);
      for (int k = 0; k < 4; ++k) {
        int j = q0i + k - 1;
        int jc = j < 0 ? 0 : (j > PN - 1 ? PN - 1 : j);
        wMT[jc * 32 + t] += (float)cubic_d(xp - (double)j);   // f32 accumulate == np M build
      }
    }
    double mseP = 0.0;
    float entf = 0.0f, ps0 = 0, ps1 = 0, ps2 = 0, ps3 = 0;
    #pragma unroll
    for (int cc = 0; cc < 4; ++cc) {
      double* hp = hupd + (4 * g + cc) * 1056 + y * 33 + x0;
      float psl = 0.0f;
      #pragma unroll
      for (int k = 0; k < 8; ++k) {
        double xr = (double)fown[cc][k] - fhat[cc][k];
        hp[k] = xr;
        mseP += xr * xr;                                  // prev scale's mse term
        float pr = 1.0f / (1.0f + __expf(400.0f * (float)xr));   // sigmoid(-400 x)
        entf -= pr * __logf(pr + 1e-5f) + (1.0f - pr) * __logf(1.0f - pr + 1e-5f);
        psl += pr;
      }
      if (cc == 0) ps0 = psl; else if (cc == 1) ps1 = psl; else if (cc == 2) ps2 = psl; else ps3 = psl;
    }
    double ent_d = (double)entf;
    #pragma unroll
    for (int off = 32; off > 0; off >>= 1) {
      mseP  += __shfl_down(mseP, off);
      ent_d += __shfl_down(ent_d, off);
      ps0 += __shfl_down(ps0, off); ps1 += __shfl_down(ps1, off);
      ps2 += __shfl_down(ps2, off); ps3 += __shfl_down(ps3, off);
    }
    if ((t & 63) == 0) {
      red[w * 8 + 0] = mseP; red[w * 8 + 1] = ent_d;
      red[w * 8 + 2] = (double)ps0; red[w * 8 + 3] = (double)ps1;
      red[w * 8 + 4] = (double)ps2; red[w * 8 + 5] = (double)ps3;
    }
  }
  __syncthreads();

  if constexpr (PN != 32) {   // flush block reductions
    if (t == 0) {
      double m = 0.0, e = 0.0;
      #pragma unroll
      for (int ww = 0; ww < 8; ++ww) { m += red[ww * 8]; e += red[ww * 8 + 1]; }
      if (si > 0) atomicAdd(&acc[(si - 1) * 18 + 0], m);
      atomicAdd(&acc[si * 18 + 1], e);
    }
    if (t < 16) {
      int gg = t >> 2, cc = t & 3;
      atomicAdd(&acc[si * 18 + 2 + t], red[(2 * gg) * 8 + 2 + cc] + red[(2 * gg + 1) * 8 + 2 + cc]);
    }
  }

  // ---------- P2: quantize (sign of f64 cell sums) ----------
  if constexpr (PN == 32) {
    double mseP = 0.0;
    float entf = 0.0f, ps0 = 0, ps1 = 0, ps2 = 0, ps3 = 0;
    unsigned bb[8] = {0, 0, 0, 0, 0, 0, 0, 0};
    #pragma unroll
    for (int cc = 0; cc < 4; ++cc) {
      float psl = 0.0f;
      #pragma unroll
      for (int k = 0; k < 8; ++k) {
        double xr = (double)fown[cc][k] - fhat[cc][k];
        if (xr > 0.0) bb[k] |= (1u << cc);
        mseP += xr * xr;
        float pr = 1.0f / (1.0f + __expf(400.0f * (float)xr));
        entf -= pr * __logf(pr + 1e-5f) + (1.0f - pr) * __logf(1.0f - pr + 1e-5f);
        psl += pr;
      }
      if (cc == 0) ps0 = psl; else if (cc == 1) ps1 = psl; else if (cc == 2) ps2 = psl; else ps3 = psl;
    }
    #pragma unroll
    for (int k = 0; k < 8; ++k)
      if (bb[k]) atomicOr(&idxL[idx32_slot(x0 + k, y)], bb[k] << (4 * g));
    double ent_d = (double)entf;
    #pragma unroll
    for (int off = 32; off > 0; off >>= 1) {
      mseP  += __shfl_down(mseP, off);
      ent_d += __shfl_down(ent_d, off);
      ps0 += __shfl_down(ps0, off); ps1 += __shfl_down(ps1, off);
      ps2 += __shfl_down(ps2, off); ps3 += __shfl_down(ps3, off);
    }
    if ((t & 63) == 0) {
      red[w * 8 + 0] = mseP; red[w * 8 + 1] = ent_d;
      red[w * 8 + 2] = (double)ps0; red[w * 8 + 3] = (double)ps1;
      red[w * 8 + 4] = (double)ps2; red[w * 8 + 5] = (double)ps3;
    }
  } else if constexpr (PN == 16) {
    int cell = t & 255;
    int i0 = (cell >> 4) * 2, j0 = (cell & 15) * 2;
    unsigned bits = 0;
    #pragma unroll
    for (int k = 0; k < 8; ++k) {
      int c = (t >> 8) + 2 * k;
      const double* hp = hupd + c * 1056 + i0 * 33 + j0;
      double s = hp[0] + hp[1] + hp[33] + hp[34];
      if (s > 0.0) bits |= (1u << c);
    }
    atomicOr(&idxL[cell], bits);
  } else if constexpr (PN == 8) {
    #pragma unroll
    for (int k = 0; k < 2; ++k) {
      int task = t + 512 * k;
      int c = task >> 6, cell = task & 63;
      const double* hp = hupd + c * 1056 + ((cell >> 3) * 4) * 33 + (cell & 7) * 4;
      double s = 0.0;
      #pragma unroll
      for (int dy = 0; dy < 4; ++dy)
        #pragma unroll
        for (int dx = 0; dx < 4; ++dx) s += hp[dy * 33 + dx];
      if (s > 0.0) atomicOr(&idxL[cell], 1u << c);
    }
  } else {   // PN 1,2,4
    constexpr int TASKS = 16 * CELLS;     // 16, 64, 256
    constexpr int G = 512 / TASKS;        // 32, 8, 2
    int p = t / G, sub = t % G;
    int c = p / CELLS, cell = p % CELLS;
    const double* hp = hupd + c * 1056 + ((cell / PN) * S) * 33 + (cell % PN) * S;
    double s = 0.0;
    for (int e = sub; e < S * S; e += G) s += hp[(e / S) * 33 + (e % S)];
    #pragma unroll
    for (int off = G / 2; off > 0; off >>= 1) s += __shfl_down(s, off, G);
    if (sub == 0 && s > 0.0) atomicOr(&idxL[cell], 1u << c);
  }
  __syncthreads();

  if constexpr (PN == 32) {   // flush scale-4 mse + scale-5 ent/ps
    if (t == 0) {
      double m = 0.0, e = 0.0;
      #pragma unroll
      for (int ww = 0; ww < 8; ++ww) { m += red[ww * 8]; e += red[ww * 8 + 1]; }
      atomicAdd(&acc[4 * 18 + 0], m);
      atomicAdd(&acc[5 * 18 + 1], e);
    }
    if (t < 16) {
      int gg = t >> 2, cc = t & 3;
      atomicAdd(&acc[5 * 18 + 2 + t], red[(2 * gg) * 8 + 2 + cc] + red[(2 * gg + 1) * 8 + 2 + cc]);
    }
  }

  // ---------- P3: hist + upsample codes -> hupd ----------
  if constexpr (PN == 32) {
    atomicAdd(&hist[5 * VOCAB + idxL[t]], 1.0f);         // swizzle bijective
    atomicAdd(&hist[5 * VOCAB + idxL[t + 512]], 1.0f);
  } else {
    if (t < CELLS) atomicAdd(&hist[(size_t)si * VOCAB + idxL[t]], 1.0f);
  }
  {
    int c2 = t >> 5, y2 = t & 31;
    double* hrow = hupd + c2 * 1056 + y2 * 33;
    if constexpr (PN == 32) {
      #pragma unroll
      for (int x = 0; x < 32; ++x)
        hrow[x] = ((idxL[idx32_slot(x, y2)] >> c2) & 1) ? 1.0 : -1.0;
    } else {
      constexpr int QC = (PN < 4) ? PN : 4;
      #pragma unroll
      for (int q0 = 0; q0 < PN; q0 += QC) {
        double tmp[QC];
        #pragma unroll
        for (int qq = 0; qq < QC; ++qq) tmp[qq] = 0.0;
        #pragma unroll
        for (int r = 0; r < PN; ++r) {
          double ww = (double)wMT[r * 32 + y2];
          #pragma unroll
          for (int qq = 0; qq < QC; ++qq) {
            double sg = ((idxL[r * PN + q0 + qq] >> c2) & 1) ? 1.0 : -1.0;
            tmp[qq] = fma(ww, sg, tmp[qq]);
          }
        }
        #pragma unroll
        for (int x = 0; x < 32; ++x) {
          double s2 = (q0 == 0) ? 0.0 : hrow[x];
          #pragma unroll
          for (int qq = 0; qq < QC; ++qq)
            s2 = fma((double)wMT[(q0 + qq) * 32 + x], tmp[qq], s2);
          hrow[x] = s2;
        }
      }
    }
  }
  __syncthreads();

  // ---------- P4: seed fhat, conv3x3 into fhat (0.5-scaled weights from SGPR) ----------
  const float* wgbase = phi_w + phi_idx * 2304;   // wave-uniform -> scalar loads
  #pragma unroll
  for (int cc = 0; cc < 4; ++cc) {
    double bh = 0.5 * (double)phi_b[phi_idx * 16 + 4 * g + cc];
    const double* hu = hupd + (4 * g + cc) * 1056 + y * 33 + x0;
    #pragma unroll
    for (int k = 0; k < 8; ++k)
      fhat[cc][k] = fhat[cc][k] + 0.5 * hu[k] + bh;
  }
  for (int ci = 0; ci < 16; ++ci) {
    const double* hbase = hupd + ci * 1056;
    #pragma unroll
    for (int dy = 0; dy < 3; ++dy) {
      int ry = y + dy - 1;
      if (ry < 0 || ry > 31) continue;
      double prow[10];
      const double* hr = hbase + ry * 33;
      // interior taps are statically in-range; only the two halo taps need selects
      prow[0] = (x0 == 0)  ? 0.0 : hr[x0 - 1];
      #pragma unroll
      for (int jj = 1; jj < 9; ++jj) prow[jj] = hr[x0 - 1 + jj];
      prow[9] = (x0 == 24) ? 0.0 : hr[x0 + 8];
      #pragma unroll
      for (int cc = 0; cc < 4; ++cc) {
        const float* wp = wgbase + ((4 * g + cc) * 16 + ci) * 9 + dy * 3;  // SGPR addr
        double w0 = 0.5 * (double)wp[0], w1 = 0.5 * (double)wp[1], w2 = 0.5 * (double)wp[2];
        #pragma unroll
        for (int k = 0; k < 8; ++k)
          fhat[cc][k] = fma(w0, prow[k], fma(w1, prow[k + 1], fma(w2, prow[k + 2], fhat[cc][k])));
      }
    }
  }
  __syncthreads();
}

__global__ __launch_bounds__(512) void lfq_all(
    const float* __restrict__ f, const float* __restrict__ phi_w,
    const float* __restrict__ phi_b, float* __restrict__ fhi,
    float* __restrict__ hist, double* __restrict__ acc)
{
  __shared__ double   hupd[16 * 1056];   // 135168 B
  __shared__ unsigned idxL[1024];
  __shared__ float    wMT[512];          // bicubic M transposed [PN][32]
  __shared__ double   red[64];           // 8 waves x 8 slots

  const int t = threadIdx.x;
  const int y = (t >> 2) & 31;
  const int x0 = (t & 3) * 8;
  const int g = __builtin_amdgcn_readfirstlane(t >> 7);   // wave-uniform -> SGPR
  const size_t ibase = (size_t)blockIdx.x * 16384;
  const int w = t >> 6;

  float fown[4][8];
  double fhat[4][8];
  #pragma unroll
  for (int cc = 0; cc < 4; ++cc) {
    const float* fp = f + ibase + (size_t)(4 * g + cc) * 1024 + y * 32 + x0;
    float4 fa = *(const float4*)fp;
    float4 fb = *(const float4*)(fp + 4);
    fown[cc][0] = fa.x; fown[cc][1] = fa.y; fown[cc][2] = fa.z; fown[cc][3] = fa.w;
    fown[cc][4] = fb.x; fown[cc][5] = fb.y; fown[cc][6] = fb.z; fown[cc][7] = fb.w;
    #pragma unroll
    for (int k = 0; k < 8; ++k) fhat[cc][k] = 0.0;
  }

  // PHI_IDX = [0,0,1,2,3,3]
  process_scale<1 >(0, 0, phi_w, phi_b, hist, acc, fown, fhat, hupd, idxL, wMT, red, t, y, g, x0);
  process_scale<2 >(1, 0, phi_w, phi_b, hist, acc, fown, fhat, hupd, idxL, wMT, red, t, y, g, x0);
  process_scale<4 >(2, 1, phi_w, phi_b, hist, acc, fown, fhat, hupd, idxL, wMT, red, t, y, g, x0);
  process_scale<8 >(3, 2, phi_w, phi_b, hist, acc, fown, fhat, hupd, idxL, wMT, red, t, y, g, x0);
  process_scale<16>(4, 3, phi_w, phi_b, hist, acc, fown, fhat, hupd, idxL, wMT, red, t, y, g, x0);
  process_scale<32>(5, 3, phi_w, phi_b, hist, acc, fown, fhat, hupd, idxL, wMT, red, t, y, g, x0);

  // final (scale 6) mse
  double mse = 0.0;
  #pragma unroll
  for (int cc = 0; cc < 4; ++cc)
    #pragma unroll
    for (int k = 0; k < 8; ++k) {
      double d = fhat[cc][k] - (double)fown[cc][k];
      mse += d * d;
    }
  #pragma unroll
  for (int off = 32; off > 0; off >>= 1) mse += __shfl_down(mse, off);
  if ((t & 63) == 0) red[w * 8] = mse;
  __syncthreads();
  if (t == 0) {
    double m = 0.0;
    #pragma unroll
    for (int ww = 0; ww < 8; ++ww) m += red[ww * 8];
    atomicAdd(&acc[5 * 18 + 0], m);
  }

  // output
  #pragma unroll
  for (int cc = 0; cc < 4; ++cc) {
    float* op = fhi + ibase + (size_t)(4 * g + cc) * 1024 + y * 32 + x0;
    *(float4*)op = make_float4((float)fhat[cc][0], (float)fhat[cc][1],
                               (float)fhat[cc][2], (float)fhat[cc][3]);
    *(float4*)(op + 4) = make_float4((float)fhat[cc][4], (float)fhat[cc][5],
                                     (float)fhat[cc][6], (float)fhat[cc][7]);
  }
}

__global__ void finalize_total(const double* __restrict__ acc, float* __restrict__ total)
{
  if (threadIdx.x == 0 && blockIdx.x == 0) {
    double vq = 0.0, ent = 0.0;
    for (int si = 0; si < 6; ++si) {
      vq += acc[si * 18 + 0];
      double pse = acc[si * 18 + 1] / (double)BHW;
      double ce = 0.0;
      for (int cc = 0; cc < 16; ++cc) {
        double ap0 = acc[si * 18 + 2 + cc] / (double)BHW;
        double ap1 = 1.0 - ap0;
        ce -= ap0 * log(ap0 + 1e-5) + ap1 * log(ap1 + 1e-5);
      }
      ent += pse - ce;
    }
    *total = (float)(1.25 * vq / ((double)NELEM * 6.0) + (0.1 / 6.0) * ent);
  }
}

extern "C" void kernel_launch(void* const* d_in, const int* in_sizes, int n_in,
                              void* d_out, int out_size, void* d_ws, size_t ws_size,
                              hipStream_t stream)
{
  const float* f     = (const float*)d_in[0];
  const float* phi_w = (const float*)d_in[1];
  const float* phi_b = (const float*)d_in[2];
  float* out   = (float*)d_out;
  float* fhi   = out;                 // fully overwritten
  float* total = out + NELEM;
  float* hist  = out + NELEM + 1;     // 6*65536
  double* acc  = (double*)d_ws;       // 108 doubles

  hipMemsetAsync((void*)(out + NELEM), 0, (size_t)(1 + 6 * VOCAB) * sizeof(float), stream);
  hipMemsetAsync(d_ws, 0, 1024, stream);

  lfq_all<<<256, 512, 0, stream>>>(f, phi_w, phi_b, fhi, hist, acc);
  finalize_total<<<1, 64, 0, stream>>>(acc, total);
}